// Round 1
// baseline (4317.934 us; speedup 1.0000x reference)
//
#include <hip/hip_runtime.h>
#include <cstdint>
#include <cstddef>

// Problem constants
#define BATCH   16
#define SEQ     512
#define NTOK    8192        // BATCH*SEQ
#define DMODEL  512
#define NHEAD   8
#define HDIM    64
#define FFDIM   2048
#define NLAYER  4
#define QT      32          // queries per attention block
#define KT      64          // keys per attention tile

// ---------------------------------------------------------------------------
// Embed: x[t][d] = sum_i feat[t][i]*w_in[i][d] + b_in[d] + posenc(pos[t], d%64)
// ---------------------------------------------------------------------------
__global__ __launch_bounds__(256) void embed_kernel(
    const float* __restrict__ feat, const int* __restrict__ pos,
    const float* __restrict__ w_in, const float* __restrict__ b_in,
    float* __restrict__ x)
{
    int idx = blockIdx.x * 256 + threadIdx.x;          // over NTOK*DMODEL
    if (idx >= NTOK * DMODEL) return;
    int t = idx >> 9;            // /512
    int d = idx & 511;
    float acc = b_in[d];
#pragma unroll
    for (int i = 0; i < 8; ++i)
        acc += feat[t * 8 + i] * w_in[i * DMODEL + d];
    int p = pos[t];
    int dl = d & 63;             // position within the 64-wide tiled block
    int pair = dl >> 1;
    // div = exp(-(2*pair) * ln(10000)/64)
    float div = expf(-(float)(2 * pair) * 0.14391156831212787f);
    float ang = (float)p * div;
    float pe = (dl & 1) ? cosf(ang) : sinf(ang);
    x[idx] = acc + pe;
}

// ---------------------------------------------------------------------------
// Tiled fp32 GEMM: C[M,N] = A[M,K] @ W[K,N] + bias (optional ReLU)
// 64x64 tile per 256-thread block, BK=16, 4x4 per thread.
// ---------------------------------------------------------------------------
template <bool RELU>
__global__ __launch_bounds__(256) void gemm_bias_kernel(
    const float* __restrict__ A, const float* __restrict__ W,
    const float* __restrict__ bias, float* __restrict__ C,
    int M, int N, int K)
{
    __shared__ float As[16][68];   // [k][m], padded stride 68 (16B-aligned rows)
    __shared__ float Bs[16][68];   // [k][n]
    const int tid = threadIdx.x;
    const int n0 = blockIdx.x * 64;
    const int m0 = blockIdx.y * 64;
    const int tx = tid & 15, ty = tid >> 4;

    float acc[4][4] = {};

    for (int k0 = 0; k0 < K; k0 += 16) {
        // A tile: 64 rows x 16 k, one float4 per thread, stored transposed
        {
            int row = tid >> 2;
            int kq  = (tid & 3) * 4;
            float4 a = *reinterpret_cast<const float4*>(
                &A[(size_t)(m0 + row) * K + k0 + kq]);
            As[kq + 0][row] = a.x;
            As[kq + 1][row] = a.y;
            As[kq + 2][row] = a.z;
            As[kq + 3][row] = a.w;
        }
        // B tile: 16 k-rows x 64 n, one float4 per thread
        {
            int kr = tid >> 4;
            int nc = (tid & 15) * 4;
            *reinterpret_cast<float4*>(&Bs[kr][nc]) =
                *reinterpret_cast<const float4*>(&W[(size_t)(k0 + kr) * N + n0 + nc]);
        }
        __syncthreads();
#pragma unroll
        for (int k = 0; k < 16; ++k) {
            float4 a = *reinterpret_cast<const float4*>(&As[k][ty * 4]);
            float4 b = *reinterpret_cast<const float4*>(&Bs[k][tx * 4]);
            float av[4] = {a.x, a.y, a.z, a.w};
            float bv[4] = {b.x, b.y, b.z, b.w};
#pragma unroll
            for (int i = 0; i < 4; ++i)
#pragma unroll
                for (int j = 0; j < 4; ++j)
                    acc[i][j] += av[i] * bv[j];
        }
        __syncthreads();
    }

    float4 bv = *reinterpret_cast<const float4*>(&bias[n0 + tx * 4]);
    float bb[4] = {bv.x, bv.y, bv.z, bv.w};
#pragma unroll
    for (int i = 0; i < 4; ++i) {
        int m = m0 + ty * 4 + i;
        float4 r;
        float v0 = acc[i][0] + bb[0];
        float v1 = acc[i][1] + bb[1];
        float v2 = acc[i][2] + bb[2];
        float v3 = acc[i][3] + bb[3];
        if (RELU) {
            v0 = fmaxf(v0, 0.f); v1 = fmaxf(v1, 0.f);
            v2 = fmaxf(v2, 0.f); v3 = fmaxf(v3, 0.f);
        }
        r.x = v0; r.y = v1; r.z = v2; r.w = v3;
        *reinterpret_cast<float4*>(&C[(size_t)m * N + n0 + tx * 4]) = r;
    }
}

// ---------------------------------------------------------------------------
// Flash-style attention. qkv layout per token: [0:512)=Q, [512:1024)=K,
// [1024:1536)=V, head h occupies cols h*64..h*64+63 of each third.
// Grid: (SEQ/QT, NHEAD, BATCH), 256 threads.
// Each query row is owned by a group of 8 threads (g = tid>>3, sub = tid&7);
// thread handles keys sub*8..+7 for scores and dims sub*8..+7 for output.
// ---------------------------------------------------------------------------
__global__ __launch_bounds__(256) void attention_kernel(
    const float* __restrict__ qkv, float* __restrict__ ctx)
{
    __shared__ float Qs[QT][68];     // float4-aligned stride
    __shared__ float Ks[KT][65];     // scalar reads; 65 avoids same-bank subs
    __shared__ float Vs[KT][68];
    __shared__ float Ps[QT][65];
    __shared__ float Pm[QT][9];

    const int tid = threadIdx.x;
    const int b = blockIdx.z, h = blockIdx.y;
    const int q0 = blockIdx.x * QT;
    const int g = tid >> 3, sub = tid & 7;
    const size_t base = (size_t)b * SEQ * (3 * DMODEL);

    // Stage Q tile (QT x HDIM)
    for (int i = tid; i < QT * (HDIM / 4); i += 256) {
        int r = i >> 4;
        int c = (i & 15) * 4;
        float4 v = *reinterpret_cast<const float4*>(
            &qkv[base + (size_t)(q0 + r) * (3 * DMODEL) + h * HDIM + c]);
        *reinterpret_cast<float4*>(&Qs[r][c]) = v;
    }

    float m_run = -1e30f, l_run = 0.f;
    float o[8] = {};
    const float scale = 0.125f;   // 1/sqrt(64)

    for (int kt0 = 0; kt0 < SEQ; kt0 += KT) {
        __syncthreads();   // previous tile fully consumed
        // Stage K and V tiles (KT x HDIM each)
        for (int i = tid; i < KT * (HDIM / 4); i += 256) {
            int r = i >> 4;
            int c = (i & 15) * 4;
            const float* kp = &qkv[base + (size_t)(kt0 + r) * (3 * DMODEL)
                                   + DMODEL + h * HDIM + c];
            float4 kv = *reinterpret_cast<const float4*>(kp);
            Ks[r][c + 0] = kv.x; Ks[r][c + 1] = kv.y;
            Ks[r][c + 2] = kv.z; Ks[r][c + 3] = kv.w;
            float4 vv = *reinterpret_cast<const float4*>(kp + DMODEL);
            *reinterpret_cast<float4*>(&Vs[r][c]) = vv;
        }
        __syncthreads();

        // Scores for query g, keys sub*8..sub*8+7
        float s[8];
        float lm = -1e30f;
#pragma unroll
        for (int j = 0; j < 8; ++j) {
            int kk = sub * 8 + j;
            float acc = 0.f;
#pragma unroll 8
            for (int d = 0; d < HDIM; ++d)
                acc += Qs[g][d] * Ks[kk][d];
            s[j] = acc * scale;
            lm = fmaxf(lm, s[j]);
        }
        Pm[g][sub] = lm;
        __syncthreads();
        float tm = Pm[g][0];
#pragma unroll
        for (int j = 1; j < 8; ++j) tm = fmaxf(tm, Pm[g][j]);
        float new_m = fmaxf(m_run, tm);
        float corr = expf(m_run - new_m);
#pragma unroll
        for (int j = 0; j < 8; ++j)
            Ps[g][sub * 8 + j] = expf(s[j] - new_m);
        m_run = new_m;
        __syncthreads();

        float psum = 0.f;
#pragma unroll
        for (int jd = 0; jd < 8; ++jd) o[jd] *= corr;
        for (int kk = 0; kk < KT; ++kk) {
            float p = Ps[g][kk];
            psum += p;
#pragma unroll
            for (int jd = 0; jd < 8; ++jd)
                o[jd] += p * Vs[kk][sub * 8 + jd];
        }
        l_run = l_run * corr + psum;
    }

    float inv = 1.f / l_run;
    int t = b * SEQ + q0 + g;
    float* op = &ctx[(size_t)t * DMODEL + h * HDIM + sub * 8];
#pragma unroll
    for (int jd = 0; jd < 8; ++jd) op[jd] = o[jd] * inv;
}

// ---------------------------------------------------------------------------
// Fused residual-add + LayerNorm, in place on x. One 64-lane wave per token.
// ---------------------------------------------------------------------------
__global__ __launch_bounds__(256) void add_ln_kernel(
    float* __restrict__ x, const float* __restrict__ resid,
    const float* __restrict__ gamma, const float* __restrict__ beta)
{
    const int wave = threadIdx.x >> 6, lane = threadIdx.x & 63;
    const int t = blockIdx.x * 4 + wave;
    float* xr = x + (size_t)t * DMODEL;
    const float* rr = resid + (size_t)t * DMODEL;

    float v[8];
    float sum = 0.f;
#pragma unroll
    for (int i = 0; i < 2; ++i) {
        float4 a = *reinterpret_cast<const float4*>(&xr[lane * 8 + i * 4]);
        float4 b = *reinterpret_cast<const float4*>(&rr[lane * 8 + i * 4]);
        v[i * 4 + 0] = a.x + b.x; v[i * 4 + 1] = a.y + b.y;
        v[i * 4 + 2] = a.z + b.z; v[i * 4 + 3] = a.w + b.w;
        sum += v[i * 4 + 0] + v[i * 4 + 1] + v[i * 4 + 2] + v[i * 4 + 3];
    }
#pragma unroll
    for (int off = 32; off; off >>= 1) sum += __shfl_xor(sum, off);
    float mean = sum * (1.f / DMODEL);
    float vs = 0.f;
#pragma unroll
    for (int i = 0; i < 8; ++i) {
        float d = v[i] - mean;
        vs += d * d;
    }
#pragma unroll
    for (int off = 32; off; off >>= 1) vs += __shfl_xor(vs, off);
    float rstd = rsqrtf(vs * (1.f / DMODEL) + 1e-5f);
#pragma unroll
    for (int i = 0; i < 8; ++i) {
        int d = lane * 8 + i;
        xr[d] = (v[i] - mean) * rstd * gamma[d] + beta[d];
    }
}

// ---------------------------------------------------------------------------
// Output projection: out[t] = dot(x[t], w_out) + b_out. Wave per token.
// ---------------------------------------------------------------------------
__global__ __launch_bounds__(256) void out_kernel(
    const float* __restrict__ x, const float* __restrict__ w,
    const float* __restrict__ b, float* __restrict__ out)
{
    const int wave = threadIdx.x >> 6, lane = threadIdx.x & 63;
    const int t = blockIdx.x * 4 + wave;
    const float* xr = x + (size_t)t * DMODEL;
    float acc = 0.f;
#pragma unroll
    for (int i = 0; i < 2; ++i) {
        float4 a = *reinterpret_cast<const float4*>(&xr[lane * 8 + i * 4]);
        float4 ww = *reinterpret_cast<const float4*>(&w[lane * 8 + i * 4]);
        acc += a.x * ww.x + a.y * ww.y + a.z * ww.z + a.w * ww.w;
    }
#pragma unroll
    for (int off = 32; off; off >>= 1) acc += __shfl_xor(acc, off);
    if (lane == 0) out[t] = acc + b[0];
}

// ---------------------------------------------------------------------------
extern "C" void kernel_launch(void* const* d_in, const int* in_sizes, int n_in,
                              void* d_out, int out_size, void* d_ws, size_t ws_size,
                              hipStream_t stream)
{
    const float* features = (const float*)d_in[0];
    const int*   pos      = (const int*)  d_in[1];
    const float* w_in     = (const float*)d_in[2];
    const float* b_in     = (const float*)d_in[3];
    const float* qkv_w    = (const float*)d_in[4];
    const float* qkv_b    = (const float*)d_in[5];
    const float* ow       = (const float*)d_in[6];
    const float* ob       = (const float*)d_in[7];
    const float* g1       = (const float*)d_in[8];
    const float* b1       = (const float*)d_in[9];
    const float* f1w      = (const float*)d_in[10];
    const float* f1b      = (const float*)d_in[11];
    const float* f2w      = (const float*)d_in[12];
    const float* f2b      = (const float*)d_in[13];
    const float* g2       = (const float*)d_in[14];
    const float* b2       = (const float*)d_in[15];
    const float* w_out    = (const float*)d_in[16];
    const float* b_out    = (const float*)d_in[17];
    float* out = (float*)d_out;

    // Workspace layout (fp32): x | big | ctx | tmp  = 112 MB total
    float* x   = (float*)d_ws;
    float* big = x   + (size_t)NTOK * DMODEL;     // holds qkv (1536) or ff hidden (2048)
    float* ctx = big + (size_t)NTOK * FFDIM;
    float* tmp = ctx + (size_t)NTOK * DMODEL;

    embed_kernel<<<(NTOK * DMODEL + 255) / 256, 256, 0, stream>>>(
        features, pos, w_in, b_in, x);

    for (int l = 0; l < NLAYER; ++l) {
        // qkv = x @ qkv_w + qkv_b   [8192,1536]
        gemm_bias_kernel<false><<<dim3((3 * DMODEL) / 64, NTOK / 64), 256, 0, stream>>>(
            x, qkv_w + (size_t)l * DMODEL * 3 * DMODEL, qkv_b + (size_t)l * 3 * DMODEL,
            big, NTOK, 3 * DMODEL, DMODEL);
        // attention -> ctx [8192,512]
        attention_kernel<<<dim3(SEQ / QT, NHEAD, BATCH), 256, 0, stream>>>(big, ctx);
        // attn_out = ctx @ ow + ob  [8192,512]
        gemm_bias_kernel<false><<<dim3(DMODEL / 64, NTOK / 64), 256, 0, stream>>>(
            ctx, ow + (size_t)l * DMODEL * DMODEL, ob + (size_t)l * DMODEL,
            tmp, NTOK, DMODEL, DMODEL);
        // x = LN(x + attn_out)
        add_ln_kernel<<<NTOK / 4, 256, 0, stream>>>(
            x, tmp, g1 + (size_t)l * DMODEL, b1 + (size_t)l * DMODEL);
        // h = relu(x @ f1w + f1b)   [8192,2048]
        gemm_bias_kernel<true><<<dim3(FFDIM / 64, NTOK / 64), 256, 0, stream>>>(
            x, f1w + (size_t)l * DMODEL * FFDIM, f1b + (size_t)l * FFDIM,
            big, NTOK, FFDIM, DMODEL);
        // ff = h @ f2w + f2b        [8192,512]
        gemm_bias_kernel<false><<<dim3(DMODEL / 64, NTOK / 64), 256, 0, stream>>>(
            big, f2w + (size_t)l * FFDIM * DMODEL, f2b + (size_t)l * DMODEL,
            tmp, NTOK, DMODEL, FFDIM);
        // x = LN(x + ff)
        add_ln_kernel<<<NTOK / 4, 256, 0, stream>>>(
            x, tmp, g2 + (size_t)l * DMODEL, b2 + (size_t)l * DMODEL);
    }

    out_kernel<<<NTOK / 4, 256, 0, stream>>>(x, w_out, b_out, out);
}

// Round 2
// 1960.964 us; speedup vs baseline: 2.2019x; 2.2019x over previous
//
#include <hip/hip_runtime.h>
#include <cstdint>
#include <cstddef>

// Problem constants
#define BATCH   16
#define SEQ     512
#define NTOK    8192        // BATCH*SEQ
#define DMODEL  512
#define NHEAD   8
#define HDIM    64
#define FFDIM   2048
#define NLAYER  4
#define QT      32          // queries per attention block
#define KT      64          // keys per attention tile

typedef unsigned short u16;
typedef __attribute__((ext_vector_type(8))) short bf16x8;
typedef __attribute__((ext_vector_type(8))) unsigned short us8;
typedef __attribute__((ext_vector_type(4))) float f32x4;

__device__ __forceinline__ float bf2f(u16 u) {
    union { float f; unsigned int i; } x; x.i = ((unsigned int)u) << 16; return x.f;
}
__device__ __forceinline__ u16 f2b(float f) {
    union { float f; unsigned int u; } a; a.f = f;
    unsigned int r = a.u + 0x7fff + ((a.u >> 16) & 1);   // round-nearest-even
    return (u16)(r >> 16);
}

// async global->LDS 16B copy (global_load_lds_dwordx4)
__device__ __forceinline__ void async_copy16(const void* g, void* l) {
    __builtin_amdgcn_global_load_lds(
        (const __attribute__((address_space(1))) unsigned int*)g,
        (__attribute__((address_space(3))) unsigned int*)l, 16, 0, 0);
}

// ---------------------------------------------------------------------------
// Embed: x[t][d] = sum_i feat[t][i]*w_in[i][d] + b_in[d] + posenc(pos[t], d%64)
// writes fp32 x and bf16 xb
// ---------------------------------------------------------------------------
__global__ __launch_bounds__(256) void embed_kernel(
    const float* __restrict__ feat, const int* __restrict__ pos,
    const float* __restrict__ w_in, const float* __restrict__ b_in,
    float* __restrict__ x, u16* __restrict__ xb)
{
    int idx = blockIdx.x * 256 + threadIdx.x;          // over NTOK*DMODEL
    if (idx >= NTOK * DMODEL) return;
    int t = idx >> 9;
    int d = idx & 511;
    float acc = b_in[d];
#pragma unroll
    for (int i = 0; i < 8; ++i)
        acc += feat[t * 8 + i] * w_in[i * DMODEL + d];
    int p = pos[t];
    int dl = d & 63;
    int pair = dl >> 1;
    float div = expf(-(float)(2 * pair) * 0.14391156831212787f);
    float ang = (float)p * div;
    float pe = (dl & 1) ? cosf(ang) : sinf(ang);
    float v = acc + pe;
    x[idx] = v;
    xb[idx] = f2b(v);
}

// ---------------------------------------------------------------------------
// Weight transpose + fp32->bf16 convert: W [K,N] -> WT [N,K], batched over L (z)
// ---------------------------------------------------------------------------
__global__ __launch_bounds__(256) void transpose_w_kernel(
    const float* __restrict__ W, u16* __restrict__ WT, int K, int N)
{
    __shared__ float t[32][33];
    const float* Wl = W + (size_t)blockIdx.z * K * N;
    u16* WTl = WT + (size_t)blockIdx.z * K * N;
    int n0 = blockIdx.x * 32, k0 = blockIdx.y * 32;
    int c = threadIdx.x & 31, r8 = threadIdx.x >> 5;
#pragma unroll
    for (int i = 0; i < 4; ++i) {
        int r = r8 + i * 8;
        t[r][c] = Wl[(size_t)(k0 + r) * N + n0 + c];
    }
    __syncthreads();
#pragma unroll
    for (int i = 0; i < 4; ++i) {
        int r = r8 + i * 8;
        WTl[(size_t)(n0 + r) * K + k0 + c] = f2b(t[c][r]);
    }
}

// ---------------------------------------------------------------------------
// bf16 MFMA GEMM (m97 structure): C[M,N] = A[M,K] @ BT[N,K]^T + bias
// A, BT row-major bf16. 128x128 tile, BK=32, 4 waves (2x2), 4x4 16x16 frags.
// OUT_BF16: store bf16, else fp32. RELU optional.
// ---------------------------------------------------------------------------
template <int OUT_BF16, int RELU>
__global__ __launch_bounds__(256) void gemm_mfma_kernel(
    const u16* __restrict__ A, const u16* __restrict__ BT,
    const float* __restrict__ bias, void* __restrict__ Cp,
    int M, int N, int K)
{
    __shared__ u16 As[128 * 32];
    __shared__ u16 Bs[128 * 32];
    const int tid = threadIdx.x;
    const int n0 = blockIdx.x * 128, m0 = blockIdx.y * 128;
    const int wid = tid >> 6, lane = tid & 63;
    const int wr = (wid >> 1) * 64, wc = (wid & 1) * 64;
    const int lr = lane & 15;             // fragment row/col index
    const int lk = (lane >> 4) * 8;       // k-offset within fragment

    f32x4 acc[4][4] = {};

    for (int kt = 0; kt < K; kt += 32) {
        __syncthreads();   // previous tile's ds_reads done
#pragma unroll
        for (int j = 0; j < 2; ++j) {
            int idx = j * 256 + tid;          // 0..511
            int row = idx >> 2;               // 0..127
            int kc = (idx & 3) * 8;           // 0,8,16,24
            async_copy16(&A[(size_t)(m0 + row) * K + kt + kc], &As[idx * 8]);
            async_copy16(&BT[(size_t)(n0 + row) * K + kt + kc], &Bs[idx * 8]);
        }
        __syncthreads();   // vmcnt(0) drained by compiler before barrier

        bf16x8 a[4], b[4];
#pragma unroll
        for (int i = 0; i < 4; ++i) {
            a[i] = *(const bf16x8*)&As[(wr + i * 16 + lr) * 32 + lk];
            b[i] = *(const bf16x8*)&Bs[(wc + i * 16 + lr) * 32 + lk];
        }
#pragma unroll
        for (int i = 0; i < 4; ++i)
#pragma unroll
            for (int j2 = 0; j2 < 4; ++j2)
                acc[i][j2] = __builtin_amdgcn_mfma_f32_16x16x32_bf16(
                    a[i], b[j2], acc[i][j2], 0, 0, 0);
    }

    // Epilogue: D[row=(lane>>4)*4+r][col=lane&15] per 16x16 fragment (m89 map)
#pragma unroll
    for (int j2 = 0; j2 < 4; ++j2) {
        int col = n0 + wc + j2 * 16 + lr;
        float bb = bias[col];
#pragma unroll
        for (int i = 0; i < 4; ++i) {
            int rbase = m0 + wr + i * 16 + (lane >> 4) * 4;
            f32x4 v = acc[i][j2];
#pragma unroll
            for (int r = 0; r < 4; ++r) {
                float val = v[r] + bb;
                if (RELU) val = fmaxf(val, 0.f);
                if (OUT_BF16)
                    ((u16*)Cp)[(size_t)(rbase + r) * N + col] = f2b(val);
                else
                    ((float*)Cp)[(size_t)(rbase + r) * N + col] = val;
            }
        }
    }
}

// ---------------------------------------------------------------------------
// Flash-style fp32 attention (unchanged compute), bf16 qkv in / bf16 ctx out.
// qkv per token: [0:512)=Q, [512:1024)=K, [1024:1536)=V (bf16).
// ---------------------------------------------------------------------------
__global__ __launch_bounds__(256) void attention_kernel(
    const u16* __restrict__ qkv, u16* __restrict__ ctx)
{
    __shared__ float Qs[QT][68];
    __shared__ float Ks[KT][65];
    __shared__ float Vs[KT][68];
    __shared__ float Ps[QT][65];
    __shared__ float Pm[QT][9];

    const int tid = threadIdx.x;
    const int b = blockIdx.z, h = blockIdx.y;
    const int q0 = blockIdx.x * QT;
    const int g = tid >> 3, sub = tid & 7;
    const size_t base = (size_t)b * SEQ * (3 * DMODEL);

    // Stage Q tile (QT x HDIM): 2048 elems, one us8 per thread
    {
        int r = tid >> 3, c = (tid & 7) * 8;
        us8 v = *(const us8*)&qkv[base + (size_t)(q0 + r) * (3 * DMODEL) + h * HDIM + c];
#pragma unroll
        for (int j = 0; j < 8; ++j) Qs[r][c + j] = bf2f(v[j]);
    }

    float m_run = -1e30f, l_run = 0.f;
    float o[8] = {};
    const float scale = 0.125f;

    for (int kt0 = 0; kt0 < SEQ; kt0 += KT) {
        __syncthreads();
        // Stage K and V tiles (KT x HDIM each): 4096 elems each
        for (int i = tid; i < KT * (HDIM / 8); i += 256) {
            int r = i >> 3, c = (i & 7) * 8;
            const u16* kp = &qkv[base + (size_t)(kt0 + r) * (3 * DMODEL)
                                 + DMODEL + h * HDIM + c];
            us8 kv = *(const us8*)kp;
            us8 vv = *(const us8*)(kp + DMODEL);
#pragma unroll
            for (int j = 0; j < 8; ++j) {
                Ks[r][c + j] = bf2f(kv[j]);
                Vs[r][c + j] = bf2f(vv[j]);
            }
        }
        __syncthreads();

        float s[8];
        float lm = -1e30f;
#pragma unroll
        for (int j = 0; j < 8; ++j) {
            int kk = sub * 8 + j;
            float acc = 0.f;
#pragma unroll 8
            for (int d = 0; d < HDIM; ++d)
                acc += Qs[g][d] * Ks[kk][d];
            s[j] = acc * scale;
            lm = fmaxf(lm, s[j]);
        }
        Pm[g][sub] = lm;
        __syncthreads();
        float tm = Pm[g][0];
#pragma unroll
        for (int j = 1; j < 8; ++j) tm = fmaxf(tm, Pm[g][j]);
        float new_m = fmaxf(m_run, tm);
        float corr = expf(m_run - new_m);
#pragma unroll
        for (int j = 0; j < 8; ++j)
            Ps[g][sub * 8 + j] = expf(s[j] - new_m);
        m_run = new_m;
        __syncthreads();

        float psum = 0.f;
#pragma unroll
        for (int jd = 0; jd < 8; ++jd) o[jd] *= corr;
        for (int kk = 0; kk < KT; ++kk) {
            float p = Ps[g][kk];
            psum += p;
#pragma unroll
            for (int jd = 0; jd < 8; ++jd)
                o[jd] += p * Vs[kk][sub * 8 + jd];
        }
        l_run = l_run * corr + psum;
    }

    float inv = 1.f / l_run;
    int t = b * SEQ + q0 + g;
    u16* op = &ctx[(size_t)t * DMODEL + h * HDIM + sub * 8];
#pragma unroll
    for (int jd = 0; jd < 8; ++jd) op[jd] = f2b(o[jd] * inv);
}

// ---------------------------------------------------------------------------
// Fused residual-add + LayerNorm, in place on x; also writes bf16 copy xb.
// One 64-lane wave per token.
// ---------------------------------------------------------------------------
__global__ __launch_bounds__(256) void add_ln_kernel(
    float* __restrict__ x, u16* __restrict__ xb, const float* __restrict__ resid,
    const float* __restrict__ gamma, const float* __restrict__ beta)
{
    const int wave = threadIdx.x >> 6, lane = threadIdx.x & 63;
    const int t = blockIdx.x * 4 + wave;
    float* xr = x + (size_t)t * DMODEL;
    u16* xbr = xb + (size_t)t * DMODEL;
    const float* rr = resid + (size_t)t * DMODEL;

    float v[8];
    float sum = 0.f;
#pragma unroll
    for (int i = 0; i < 2; ++i) {
        float4 a = *reinterpret_cast<const float4*>(&xr[lane * 8 + i * 4]);
        float4 b = *reinterpret_cast<const float4*>(&rr[lane * 8 + i * 4]);
        v[i * 4 + 0] = a.x + b.x; v[i * 4 + 1] = a.y + b.y;
        v[i * 4 + 2] = a.z + b.z; v[i * 4 + 3] = a.w + b.w;
        sum += v[i * 4 + 0] + v[i * 4 + 1] + v[i * 4 + 2] + v[i * 4 + 3];
    }
#pragma unroll
    for (int off = 32; off; off >>= 1) sum += __shfl_xor(sum, off);
    float mean = sum * (1.f / DMODEL);
    float vs = 0.f;
#pragma unroll
    for (int i = 0; i < 8; ++i) {
        float d = v[i] - mean;
        vs += d * d;
    }
#pragma unroll
    for (int off = 32; off; off >>= 1) vs += __shfl_xor(vs, off);
    float rstd = rsqrtf(vs * (1.f / DMODEL) + 1e-5f);
#pragma unroll
    for (int i = 0; i < 8; ++i) {
        int d = lane * 8 + i;
        float val = (v[i] - mean) * rstd * gamma[d] + beta[d];
        xr[d] = val;
        xbr[d] = f2b(val);
    }
}

// ---------------------------------------------------------------------------
// Output projection: out[t] = dot(x[t], w_out) + b_out. Wave per token.
// ---------------------------------------------------------------------------
__global__ __launch_bounds__(256) void out_kernel(
    const float* __restrict__ x, const float* __restrict__ w,
    const float* __restrict__ b, float* __restrict__ out)
{
    const int wave = threadIdx.x >> 6, lane = threadIdx.x & 63;
    const int t = blockIdx.x * 4 + wave;
    const float* xr = x + (size_t)t * DMODEL;
    float acc = 0.f;
#pragma unroll
    for (int i = 0; i < 2; ++i) {
        float4 a = *reinterpret_cast<const float4*>(&xr[lane * 8 + i * 4]);
        float4 ww = *reinterpret_cast<const float4*>(&w[lane * 8 + i * 4]);
        acc += a.x * ww.x + a.y * ww.y + a.z * ww.z + a.w * ww.w;
    }
#pragma unroll
    for (int off = 32; off; off >>= 1) acc += __shfl_xor(acc, off);
    if (lane == 0) out[t] = acc + b[0];
}

// ---------------------------------------------------------------------------
extern "C" void kernel_launch(void* const* d_in, const int* in_sizes, int n_in,
                              void* d_out, int out_size, void* d_ws, size_t ws_size,
                              hipStream_t stream)
{
    const float* features = (const float*)d_in[0];
    const int*   pos      = (const int*)  d_in[1];
    const float* w_in     = (const float*)d_in[2];
    const float* b_in     = (const float*)d_in[3];
    const float* qkv_w    = (const float*)d_in[4];
    const float* qkv_b    = (const float*)d_in[5];
    const float* ow       = (const float*)d_in[6];
    const float* ob       = (const float*)d_in[7];
    const float* g1       = (const float*)d_in[8];
    const float* b1       = (const float*)d_in[9];
    const float* ff1w     = (const float*)d_in[10];
    const float* ff1b     = (const float*)d_in[11];
    const float* ff2w     = (const float*)d_in[12];
    const float* ff2b     = (const float*)d_in[13];
    const float* g2       = (const float*)d_in[14];
    const float* b2       = (const float*)d_in[15];
    const float* w_out    = (const float*)d_in[16];
    const float* b_out    = (const float*)d_in[17];
    float* out = (float*)d_out;

    // Workspace layout (105.2 MB total)
    char* p = (char*)d_ws;
    auto alloc = [&](size_t bytes) { char* r = p; p += (bytes + 255) & ~(size_t)255; return r; };
    float* x   = (float*)alloc((size_t)NTOK * DMODEL * 4);          // 16 MB
    u16*   xb  = (u16*)  alloc((size_t)NTOK * DMODEL * 2);          // 8 MB
    u16*   big = (u16*)  alloc((size_t)NTOK * FFDIM * 2);           // 32 MB (qkv bf16 24MB / h bf16 32MB)
    u16*   ctx = (u16*)  alloc((size_t)NTOK * DMODEL * 2);          // 8 MB
    float* tmp = (float*)alloc((size_t)NTOK * DMODEL * 4);          // 16 MB
    u16* wqkvT = (u16*)alloc((size_t)NLAYER * DMODEL * 3 * DMODEL * 2);  // 6.3 MB
    u16* owT   = (u16*)alloc((size_t)NLAYER * DMODEL * DMODEL * 2);      // 2.1 MB
    u16* f1wT  = (u16*)alloc((size_t)NLAYER * DMODEL * FFDIM * 2);       // 8.4 MB
    u16* f2wT  = (u16*)alloc((size_t)NLAYER * FFDIM * DMODEL * 2);       // 8.4 MB

    // Weight transpose+convert (once per call; graph-replayed)
    transpose_w_kernel<<<dim3(3 * DMODEL / 32, DMODEL / 32, NLAYER), 256, 0, stream>>>(
        qkv_w, wqkvT, DMODEL, 3 * DMODEL);
    transpose_w_kernel<<<dim3(DMODEL / 32, DMODEL / 32, NLAYER), 256, 0, stream>>>(
        ow, owT, DMODEL, DMODEL);
    transpose_w_kernel<<<dim3(FFDIM / 32, DMODEL / 32, NLAYER), 256, 0, stream>>>(
        ff1w, f1wT, DMODEL, FFDIM);
    transpose_w_kernel<<<dim3(DMODEL / 32, FFDIM / 32, NLAYER), 256, 0, stream>>>(
        ff2w, f2wT, FFDIM, DMODEL);

    embed_kernel<<<(NTOK * DMODEL + 255) / 256, 256, 0, stream>>>(
        features, pos, w_in, b_in, x, xb);

    for (int l = 0; l < NLAYER; ++l) {
        // qkv = xb @ qkv_w + qkv_b -> bf16 [8192,1536]
        gemm_mfma_kernel<1, 0><<<dim3(3 * DMODEL / 128, NTOK / 128), 256, 0, stream>>>(
            xb, wqkvT + (size_t)l * DMODEL * 3 * DMODEL, qkv_b + (size_t)l * 3 * DMODEL,
            big, NTOK, 3 * DMODEL, DMODEL);
        // attention -> ctx bf16 [8192,512]
        attention_kernel<<<dim3(SEQ / QT, NHEAD, BATCH), 256, 0, stream>>>(big, ctx);
        // attn_out = ctx @ ow + ob -> fp32 tmp
        gemm_mfma_kernel<0, 0><<<dim3(DMODEL / 128, NTOK / 128), 256, 0, stream>>>(
            ctx, owT + (size_t)l * DMODEL * DMODEL, ob + (size_t)l * DMODEL,
            tmp, NTOK, DMODEL, DMODEL);
        // x = LN(x + attn_out); xb = bf16(x)
        add_ln_kernel<<<NTOK / 4, 256, 0, stream>>>(
            x, xb, tmp, g1 + (size_t)l * DMODEL, b1 + (size_t)l * DMODEL);
        // h = relu(xb @ ff1w + ff1b) -> bf16 [8192,2048]
        gemm_mfma_kernel<1, 1><<<dim3(FFDIM / 128, NTOK / 128), 256, 0, stream>>>(
            xb, f1wT + (size_t)l * DMODEL * FFDIM, ff1b + (size_t)l * FFDIM,
            big, NTOK, FFDIM, DMODEL);
        // ff = h @ ff2w + ff2b -> fp32 tmp
        gemm_mfma_kernel<0, 0><<<dim3(DMODEL / 128, NTOK / 128), 256, 0, stream>>>(
            big, f2wT + (size_t)l * FFDIM * DMODEL, ff2b + (size_t)l * DMODEL,
            tmp, NTOK, DMODEL, FFDIM);
        // x = LN(x + ff); xb = bf16(x)
        add_ln_kernel<<<NTOK / 4, 256, 0, stream>>>(
            x, xb, tmp, g2 + (size_t)l * DMODEL, b2 + (size_t)l * DMODEL);
    }

    out_kernel<<<NTOK / 4, 256, 0, stream>>>(x, w_out, b_out, out);
}

// Round 3
// 771.751 us; speedup vs baseline: 5.5950x; 2.5409x over previous
//
#include <hip/hip_runtime.h>
#include <cstdint>
#include <cstddef>

// Problem constants
#define BATCH   16
#define SEQ     512
#define NTOK    8192        // BATCH*SEQ
#define DMODEL  512
#define NHEAD   8
#define HDIM    64
#define FFDIM   2048
#define NLAYER  4

typedef unsigned short u16;
typedef __attribute__((ext_vector_type(8))) short bf16x8;
typedef __attribute__((ext_vector_type(8))) unsigned short us8;
typedef __attribute__((ext_vector_type(4))) float f32x4;

__device__ __forceinline__ float bf2f(u16 u) {
    union { float f; unsigned int i; } x; x.i = ((unsigned int)u) << 16; return x.f;
}
__device__ __forceinline__ u16 f2b(float f) {
    union { float f; unsigned int u; } a; a.f = f;
    unsigned int r = a.u + 0x7fff + ((a.u >> 16) & 1);   // round-nearest-even
    return (u16)(r >> 16);
}

// async global->LDS 16B copy (global_load_lds_dwordx4)
__device__ __forceinline__ void async_copy16(const void* g, void* l) {
    __builtin_amdgcn_global_load_lds(
        (const __attribute__((address_space(1))) unsigned int*)g,
        (__attribute__((address_space(3))) unsigned int*)l, 16, 0, 0);
}

// ---------------------------------------------------------------------------
// Embed: x[t][d] = sum_i feat[t][i]*w_in[i][d] + b_in[d] + posenc(pos[t], d%64)
// writes fp32 x and bf16 xb
// ---------------------------------------------------------------------------
__global__ __launch_bounds__(256) void embed_kernel(
    const float* __restrict__ feat, const int* __restrict__ pos,
    const float* __restrict__ w_in, const float* __restrict__ b_in,
    float* __restrict__ x, u16* __restrict__ xb)
{
    int idx = blockIdx.x * 256 + threadIdx.x;          // over NTOK*DMODEL
    if (idx >= NTOK * DMODEL) return;
    int t = idx >> 9;
    int d = idx & 511;
    float acc = b_in[d];
#pragma unroll
    for (int i = 0; i < 8; ++i)
        acc += feat[t * 8 + i] * w_in[i * DMODEL + d];
    int p = pos[t];
    int dl = d & 63;
    int pair = dl >> 1;
    float div = expf(-(float)(2 * pair) * 0.14391156831212787f);
    float ang = (float)p * div;
    float pe = (dl & 1) ? cosf(ang) : sinf(ang);
    float v = acc + pe;
    x[idx] = v;
    xb[idx] = f2b(v);
}

// ---------------------------------------------------------------------------
// Weight transpose + fp32->bf16 convert: W [K,N] -> WT [N,K], batched over L (z)
// ---------------------------------------------------------------------------
__global__ __launch_bounds__(256) void transpose_w_kernel(
    const float* __restrict__ W, u16* __restrict__ WT, int K, int N)
{
    __shared__ float t[32][33];
    const float* Wl = W + (size_t)blockIdx.z * K * N;
    u16* WTl = WT + (size_t)blockIdx.z * K * N;
    int n0 = blockIdx.x * 32, k0 = blockIdx.y * 32;
    int c = threadIdx.x & 31, r8 = threadIdx.x >> 5;
#pragma unroll
    for (int i = 0; i < 4; ++i) {
        int r = r8 + i * 8;
        t[r][c] = Wl[(size_t)(k0 + r) * N + n0 + c];
    }
    __syncthreads();
#pragma unroll
    for (int i = 0; i < 4; ++i) {
        int r = r8 + i * 8;
        WTl[(size_t)(n0 + r) * K + k0 + c] = f2b(t[c][r]);
    }
}

// ---------------------------------------------------------------------------
// bf16 MFMA GEMM (m97 structure): C[M,N] = A[M,K] @ BT[N,K]^T + bias
// ---------------------------------------------------------------------------
template <int OUT_BF16, int RELU>
__global__ __launch_bounds__(256) void gemm_mfma_kernel(
    const u16* __restrict__ A, const u16* __restrict__ BT,
    const float* __restrict__ bias, void* __restrict__ Cp,
    int M, int N, int K)
{
    __shared__ u16 As[128 * 32];
    __shared__ u16 Bs[128 * 32];
    const int tid = threadIdx.x;
    const int n0 = blockIdx.x * 128, m0 = blockIdx.y * 128;
    const int wid = tid >> 6, lane = tid & 63;
    const int wr = (wid >> 1) * 64, wc = (wid & 1) * 64;
    const int lr = lane & 15;             // fragment row/col index
    const int lk = (lane >> 4) * 8;       // k-offset within fragment

    f32x4 acc[4][4] = {};

    for (int kt = 0; kt < K; kt += 32) {
        __syncthreads();
#pragma unroll
        for (int j = 0; j < 2; ++j) {
            int idx = j * 256 + tid;
            int row = idx >> 2;
            int kc = (idx & 3) * 8;
            async_copy16(&A[(size_t)(m0 + row) * K + kt + kc], &As[idx * 8]);
            async_copy16(&BT[(size_t)(n0 + row) * K + kt + kc], &Bs[idx * 8]);
        }
        __syncthreads();

        bf16x8 a[4], b[4];
#pragma unroll
        for (int i = 0; i < 4; ++i) {
            a[i] = *(const bf16x8*)&As[(wr + i * 16 + lr) * 32 + lk];
            b[i] = *(const bf16x8*)&Bs[(wc + i * 16 + lr) * 32 + lk];
        }
#pragma unroll
        for (int i = 0; i < 4; ++i)
#pragma unroll
            for (int j2 = 0; j2 < 4; ++j2)
                acc[i][j2] = __builtin_amdgcn_mfma_f32_16x16x32_bf16(
                    a[i], b[j2], acc[i][j2], 0, 0, 0);
    }

#pragma unroll
    for (int j2 = 0; j2 < 4; ++j2) {
        int col = n0 + wc + j2 * 16 + lr;
        float bb = bias[col];
#pragma unroll
        for (int i = 0; i < 4; ++i) {
            int rbase = m0 + wr + i * 16 + (lane >> 4) * 4;
            f32x4 v = acc[i][j2];
#pragma unroll
            for (int r = 0; r < 4; ++r) {
                float val = v[r] + bb;
                if (RELU) val = fmaxf(val, 0.f);
                if (OUT_BF16)
                    ((u16*)Cp)[(size_t)(rbase + r) * N + col] = f2b(val);
                else
                    ((float*)Cp)[(size_t)(rbase + r) * N + col] = val;
            }
        }
    }
}

// ---------------------------------------------------------------------------
// MFMA flash attention. qkv bf16 per token: [0:512)=Q, [512:1024)=K, [1024:1536)=V.
// Grid: (SEQ/64, NHEAD, BATCH), 256 threads = 4 waves; wave w owns q-rows
// [q0+w*16, q0+w*16+16). K/V iterated in 64-key tiles, online softmax.
// Q/K in LDS with chunk^=(row&7) swizzle (staged via pre-swizzled global src).
// V staged transposed Vt[d][k] (pad 72). P goes through per-wave LDS to reach
// the MFMA A-fragment layout.
// ---------------------------------------------------------------------------
__global__ __launch_bounds__(256) void attention_mfma_kernel(
    const u16* __restrict__ qkv, u16* __restrict__ ctx)
{
    __shared__ __align__(16) u16 Qs[64 * 64];
    __shared__ __align__(16) u16 Ks[64 * 64];
    __shared__ __align__(16) u16 Vt[64][72];
    __shared__ __align__(16) u16 Ps[4][16][72];

    const int tid = threadIdx.x;
    const int b = blockIdx.z, h = blockIdx.y;
    const int q0 = blockIdx.x * 64;
    const int wid = tid >> 6, lane = tid & 63;
    const int lr = lane & 15;          // fragment row/col
    const int lk16 = lane >> 4;        // 0..3 (k-chunk within fragment)
    const size_t base = (size_t)b * SEQ * 1536;

    // Stage Q (swizzled source -> linear LDS): chunk c holds global colchunk (c&7)^(row&7)
#pragma unroll
    for (int j = 0; j < 2; ++j) {
        int c = j * 256 + tid;
        int row = c >> 3;
        int sc8 = ((c & 7) ^ (row & 7)) * 8;
        async_copy16(&qkv[base + (size_t)(q0 + row) * 1536 + h * 64 + sc8], &Qs[c * 8]);
    }

    float m_r[4] = {-1e30f, -1e30f, -1e30f, -1e30f};
    float l_r[4] = {0.f, 0.f, 0.f, 0.f};
    f32x4 o_acc[4] = {};

    for (int kt = 0; kt < SEQ; kt += 64) {
        __syncthreads();   // previous tile fully consumed (also covers Q staging)
        // stage K (swizzled source, async)
#pragma unroll
        for (int j = 0; j < 2; ++j) {
            int c = j * 256 + tid;
            int row = c >> 3;
            int sc8 = ((c & 7) ^ (row & 7)) * 8;
            async_copy16(&qkv[base + (size_t)(kt + row) * 1536 + 512 + h * 64 + sc8], &Ks[c * 8]);
        }
        // stage V transposed: Vt[d][k]
#pragma unroll
        for (int j = 0; j < 2; ++j) {
            int i = j * 256 + tid;
            int r = i >> 3, c0 = (i & 7) * 8;
            us8 v = *(const us8*)&qkv[base + (size_t)(kt + r) * 1536 + 1024 + h * 64 + c0];
#pragma unroll
            for (int e = 0; e < 8; ++e) Vt[c0 + e][r] = v[e];
        }
        __syncthreads();

        // QK^T: 16 q-rows x 64 keys per wave
        f32x4 sc[4] = {};
        const int qrow = wid * 16 + lr;
#pragma unroll
        for (int ks = 0; ks < 2; ++ks) {
            bf16x8 aq = *(const bf16x8*)&Qs[qrow * 64 + ((ks * 4 + lk16) ^ (qrow & 7)) * 8];
#pragma unroll
            for (int j = 0; j < 4; ++j) {
                int krow = j * 16 + lr;
                bf16x8 bk = *(const bf16x8*)&Ks[krow * 64 + ((ks * 4 + lk16) ^ (krow & 7)) * 8];
                sc[j] = __builtin_amdgcn_mfma_f32_16x16x32_bf16(aq, bk, sc[j], 0, 0, 0);
            }
        }

        // online softmax; lane holds rows (lk16*4+r), cols j*16+lr
        float pf[4][4];
#pragma unroll
        for (int r = 0; r < 4; ++r) {
            float mx = fmaxf(fmaxf(sc[0][r], sc[1][r]), fmaxf(sc[2][r], sc[3][r]));
#pragma unroll
            for (int m = 1; m < 16; m <<= 1)
                mx = fmaxf(mx, __shfl_xor(mx, m));
            float nm = fmaxf(m_r[r], mx * 0.125f);
            float s0 = 0.f;
#pragma unroll
            for (int j = 0; j < 4; ++j) {
                float p = __expf(sc[j][r] * 0.125f - nm);
                pf[j][r] = p;
                s0 += p;
            }
#pragma unroll
            for (int m = 1; m < 16; m <<= 1)
                s0 += __shfl_xor(s0, m);
            float corr = __expf(m_r[r] - nm);
            l_r[r] = l_r[r] * corr + s0;
            m_r[r] = nm;
#pragma unroll
            for (int j = 0; j < 4; ++j)
                o_acc[j][r] *= corr;
        }

        // P (C-layout) -> per-wave LDS (A-source layout)
#pragma unroll
        for (int j = 0; j < 4; ++j)
#pragma unroll
            for (int r = 0; r < 4; ++r)
                Ps[wid][lk16 * 4 + r][j * 16 + lr] = f2b(pf[j][r]);

        // PV: o[16q x 64d] += P[16q x 64k] @ V[64k x 64d]
#pragma unroll
        for (int kk = 0; kk < 2; ++kk) {
            bf16x8 ap = *(const bf16x8*)&Ps[wid][lr][kk * 32 + lk16 * 8];
#pragma unroll
            for (int j2 = 0; j2 < 4; ++j2) {
                bf16x8 bv = *(const bf16x8*)&Vt[j2 * 16 + lr][kk * 32 + lk16 * 8];
                o_acc[j2] = __builtin_amdgcn_mfma_f32_16x16x32_bf16(ap, bv, o_acc[j2], 0, 0, 0);
            }
        }
    }

    // epilogue: out[q][d] = o/l, bf16
#pragma unroll
    for (int r = 0; r < 4; ++r) {
        float inv = 1.f / l_r[r];
        int t = b * SEQ + q0 + wid * 16 + lk16 * 4 + r;
        u16* op = &ctx[(size_t)t * DMODEL + h * 64];
#pragma unroll
        for (int j2 = 0; j2 < 4; ++j2)
            op[j2 * 16 + lr] = f2b(o_acc[j2][r] * inv);
    }
}

// ---------------------------------------------------------------------------
// Fused residual-add + LayerNorm, in place on x; also writes bf16 copy xb.
// ---------------------------------------------------------------------------
__global__ __launch_bounds__(256) void add_ln_kernel(
    float* __restrict__ x, u16* __restrict__ xb, const float* __restrict__ resid,
    const float* __restrict__ gamma, const float* __restrict__ beta)
{
    const int wave = threadIdx.x >> 6, lane = threadIdx.x & 63;
    const int t = blockIdx.x * 4 + wave;
    float* xr = x + (size_t)t * DMODEL;
    u16* xbr = xb + (size_t)t * DMODEL;
    const float* rr = resid + (size_t)t * DMODEL;

    float v[8];
    float sum = 0.f;
#pragma unroll
    for (int i = 0; i < 2; ++i) {
        float4 a = *reinterpret_cast<const float4*>(&xr[lane * 8 + i * 4]);
        float4 b = *reinterpret_cast<const float4*>(&rr[lane * 8 + i * 4]);
        v[i * 4 + 0] = a.x + b.x; v[i * 4 + 1] = a.y + b.y;
        v[i * 4 + 2] = a.z + b.z; v[i * 4 + 3] = a.w + b.w;
        sum += v[i * 4 + 0] + v[i * 4 + 1] + v[i * 4 + 2] + v[i * 4 + 3];
    }
#pragma unroll
    for (int off = 32; off; off >>= 1) sum += __shfl_xor(sum, off);
    float mean = sum * (1.f / DMODEL);
    float vs = 0.f;
#pragma unroll
    for (int i = 0; i < 8; ++i) {
        float d = v[i] - mean;
        vs += d * d;
    }
#pragma unroll
    for (int off = 32; off; off >>= 1) vs += __shfl_xor(vs, off);
    float rstd = rsqrtf(vs * (1.f / DMODEL) + 1e-5f);
#pragma unroll
    for (int i = 0; i < 8; ++i) {
        int d = lane * 8 + i;
        float val = (v[i] - mean) * rstd * gamma[d] + beta[d];
        xr[d] = val;
        xbr[d] = f2b(val);
    }
}

// ---------------------------------------------------------------------------
// Output projection: out[t] = dot(x[t], w_out) + b_out. Wave per token.
// ---------------------------------------------------------------------------
__global__ __launch_bounds__(256) void out_kernel(
    const float* __restrict__ x, const float* __restrict__ w,
    const float* __restrict__ b, float* __restrict__ out)
{
    const int wave = threadIdx.x >> 6, lane = threadIdx.x & 63;
    const int t = blockIdx.x * 4 + wave;
    const float* xr = x + (size_t)t * DMODEL;
    float acc = 0.f;
#pragma unroll
    for (int i = 0; i < 2; ++i) {
        float4 a = *reinterpret_cast<const float4*>(&xr[lane * 8 + i * 4]);
        float4 ww = *reinterpret_cast<const float4*>(&w[lane * 8 + i * 4]);
        acc += a.x * ww.x + a.y * ww.y + a.z * ww.z + a.w * ww.w;
    }
#pragma unroll
    for (int off = 32; off; off >>= 1) acc += __shfl_xor(acc, off);
    if (lane == 0) out[t] = acc + b[0];
}

// ---------------------------------------------------------------------------
extern "C" void kernel_launch(void* const* d_in, const int* in_sizes, int n_in,
                              void* d_out, int out_size, void* d_ws, size_t ws_size,
                              hipStream_t stream)
{
    const float* features = (const float*)d_in[0];
    const int*   pos      = (const int*)  d_in[1];
    const float* w_in     = (const float*)d_in[2];
    const float* b_in     = (const float*)d_in[3];
    const float* qkv_w    = (const float*)d_in[4];
    const float* qkv_b    = (const float*)d_in[5];
    const float* ow       = (const float*)d_in[6];
    const float* ob       = (const float*)d_in[7];
    const float* g1       = (const float*)d_in[8];
    const float* b1       = (const float*)d_in[9];
    const float* ff1w     = (const float*)d_in[10];
    const float* ff1b     = (const float*)d_in[11];
    const float* ff2w     = (const float*)d_in[12];
    const float* ff2b     = (const float*)d_in[13];
    const float* g2       = (const float*)d_in[14];
    const float* b2       = (const float*)d_in[15];
    const float* w_out    = (const float*)d_in[16];
    const float* b_out    = (const float*)d_in[17];
    float* out = (float*)d_out;

    // Workspace layout (105.2 MB total)
    char* p = (char*)d_ws;
    auto alloc = [&](size_t bytes) { char* r = p; p += (bytes + 255) & ~(size_t)255; return r; };
    float* x   = (float*)alloc((size_t)NTOK * DMODEL * 4);
    u16*   xb  = (u16*)  alloc((size_t)NTOK * DMODEL * 2);
    u16*   big = (u16*)  alloc((size_t)NTOK * FFDIM * 2);
    u16*   ctx = (u16*)  alloc((size_t)NTOK * DMODEL * 2);
    float* tmp = (float*)alloc((size_t)NTOK * DMODEL * 4);
    u16* wqkvT = (u16*)alloc((size_t)NLAYER * DMODEL * 3 * DMODEL * 2);
    u16* owT   = (u16*)alloc((size_t)NLAYER * DMODEL * DMODEL * 2);
    u16* f1wT  = (u16*)alloc((size_t)NLAYER * DMODEL * FFDIM * 2);
    u16* f2wT  = (u16*)alloc((size_t)NLAYER * FFDIM * DMODEL * 2);

    // Weight transpose+convert (once per call; graph-replayed)
    transpose_w_kernel<<<dim3(3 * DMODEL / 32, DMODEL / 32, NLAYER), 256, 0, stream>>>(
        qkv_w, wqkvT, DMODEL, 3 * DMODEL);
    transpose_w_kernel<<<dim3(DMODEL / 32, DMODEL / 32, NLAYER), 256, 0, stream>>>(
        ow, owT, DMODEL, DMODEL);
    transpose_w_kernel<<<dim3(FFDIM / 32, DMODEL / 32, NLAYER), 256, 0, stream>>>(
        ff1w, f1wT, DMODEL, FFDIM);
    transpose_w_kernel<<<dim3(DMODEL / 32, FFDIM / 32, NLAYER), 256, 0, stream>>>(
        ff2w, f2wT, FFDIM, DMODEL);

    embed_kernel<<<(NTOK * DMODEL + 255) / 256, 256, 0, stream>>>(
        features, pos, w_in, b_in, x, xb);

    for (int l = 0; l < NLAYER; ++l) {
        gemm_mfma_kernel<1, 0><<<dim3(3 * DMODEL / 128, NTOK / 128), 256, 0, stream>>>(
            xb, wqkvT + (size_t)l * DMODEL * 3 * DMODEL, qkv_b + (size_t)l * 3 * DMODEL,
            big, NTOK, 3 * DMODEL, DMODEL);
        attention_mfma_kernel<<<dim3(SEQ / 64, NHEAD, BATCH), 256, 0, stream>>>(big, ctx);
        gemm_mfma_kernel<0, 0><<<dim3(DMODEL / 128, NTOK / 128), 256, 0, stream>>>(
            ctx, owT + (size_t)l * DMODEL * DMODEL, ob + (size_t)l * DMODEL,
            tmp, NTOK, DMODEL, DMODEL);
        add_ln_kernel<<<NTOK / 4, 256, 0, stream>>>(
            x, xb, tmp, g1 + (size_t)l * DMODEL, b1 + (size_t)l * DMODEL);
        gemm_mfma_kernel<1, 1><<<dim3(FFDIM / 128, NTOK / 128), 256, 0, stream>>>(
            xb, f1wT + (size_t)l * DMODEL * FFDIM, ff1b + (size_t)l * FFDIM,
            big, NTOK, FFDIM, DMODEL);
        gemm_mfma_kernel<0, 0><<<dim3(DMODEL / 128, NTOK / 128), 256, 0, stream>>>(
            big, f2wT + (size_t)l * FFDIM * DMODEL, ff2b + (size_t)l * DMODEL,
            tmp, NTOK, DMODEL, FFDIM);
        add_ln_kernel<<<NTOK / 4, 256, 0, stream>>>(
            x, xb, tmp, g2 + (size_t)l * DMODEL, b2 + (size_t)l * DMODEL);
    }

    out_kernel<<<NTOK / 4, 256, 0, stream>>>(x, w_out, b_out, out);
}